// Round 3
// baseline (2405.176 us; speedup 1.0000x reference)
//
#include <hip/hip_runtime.h>

#define BB 64
#define TT 2048
#define DD 256
#define HH 256

typedef unsigned int u32;
typedef _Float16 h2 __attribute__((ext_vector_type(2)));
typedef __fp16 fp16x2 __attribute__((ext_vector_type(2)));
typedef _Float16 h8 __attribute__((ext_vector_type(8)));
typedef float f32x4 __attribute__((ext_vector_type(4)));

// f16 transposed weights [z][n][k], z=0: Wx, z=1: Wg  (256 KiB, module-static)
__device__ __align__(16) _Float16 wt_g[2][HH * DD];

// ---------- fast math helpers ----------
__device__ inline float ex2(float x) {
#if __has_builtin(__builtin_amdgcn_exp2f)
  return __builtin_amdgcn_exp2f(x);
#else
  return exp2f(x);
#endif
}
__device__ inline float rcp_(float x) {
#if __has_builtin(__builtin_amdgcn_rcpf)
  return __builtin_amdgcn_rcpf(x);
#else
  return 1.0f / x;
#endif
}
__device__ inline float rsq_(float x) {
#if __has_builtin(__builtin_amdgcn_rsqf)
  return __builtin_amdgcn_rsqf(x);
#else
  return rsqrtf(x);
#endif
}
__device__ inline float tanh_fast(float x) {
  // tanh(x) = 1 - 2/(e^{2x}+1); saturates correctly for |x| large
  float e = ex2(x * 2.8853900817779268f);  // e^{2x} = 2^{2x*log2(e)}
  return 1.0f - 2.0f * rcp_(e + 1.0f);
}
__device__ inline float sigmoid_fast(float x) {
  return rcp_(1.0f + ex2(-1.4426950408889634f * x));
}
__device__ inline h2 bch2(u32 u) { return __builtin_bit_cast(h2, u); }
__device__ inline float lo16f(u32 u) { return (float)bch2(u)[0]; }
__device__ inline float hi16f(u32 u) { return (float)bch2(u)[1]; }
__device__ inline float dot2_(u32 a, u32 b, float c) {
#if __has_builtin(__builtin_amdgcn_fdot2)
  return __builtin_amdgcn_fdot2(bch2(a), bch2(b), c, false);
#else
  h2 ha = bch2(a), hb = bch2(b);
  c = fmaf((float)ha[0], (float)hb[0], c);
  return fmaf((float)ha[1], (float)hb[1], c);
#endif
}
__device__ inline u32 pk16(float a, float b) {
  fp16x2 p = __builtin_amdgcn_cvt_pkrtz(a, b);
  return __builtin_bit_cast(u32, p);
}

// ---------- kernel 1: transpose weights to f16 [n][k] ----------
__global__ void prep_wt_kernel(const float* __restrict__ Wx,
                               const float* __restrict__ Wg) {
  const int n = blockIdx.x, z = blockIdx.y, k = threadIdx.x;
  const float* __restrict__ W = z ? Wg : Wx;
  wt_g[z][n * DD + k] = (_Float16)W[k * HH + n];
}

// ---------- kernel 2: fused xp/gate GEMM -> packed (f16 xp, f16 gate) in d_out ----------
// grid: (4, 1024): blockIdx.x -> {z = &1, by = >>1}; blockIdx.y -> M-tile (128 rows)
__global__ __launch_bounds__(256) void gemm_kernel(
    const float* __restrict__ x, const float* __restrict__ g,
    const float* __restrict__ bgv, _Float16* __restrict__ out) {
  const int zb = blockIdx.x;
  const int z = zb & 1, by = zb >> 1;
  const int bx = blockIdx.y;
  const float* __restrict__ A = z ? g : x;
  const int tid = threadIdx.x;
  const int lane = tid & 63, wave = tid >> 6;
  const int wm = wave >> 1, wn = wave & 1;
  const int fr = lane & 15, fq = lane >> 4;

  __shared__ __align__(16) _Float16 As[128 * 40];  // rows padded to 40 halves (80 B)

  f32x4 acc[4][4];
#pragma unroll
  for (int i = 0; i < 4; ++i)
#pragma unroll
    for (int j = 0; j < 4; ++j) acc[i][j] = (f32x4)0.0f;

  const int m_st = tid >> 1, part = tid & 1;
  const float* __restrict__ srcA =
      A + (size_t)(bx * 128 + m_st) * DD + part * 16;

  for (int kt = 0; kt < 8; ++kt) {
    // stage A tile (128x32 f32 -> f16, padded rows)
    const float4* s4 = (const float4*)(srcA + kt * 32);
    float4 v0 = s4[0], v1 = s4[1], v2 = s4[2], v3 = s4[3];
    uint4 w0, w1;
    w0.x = pk16(v0.x, v0.y); w0.y = pk16(v0.z, v0.w);
    w0.z = pk16(v1.x, v1.y); w0.w = pk16(v1.z, v1.w);
    w1.x = pk16(v2.x, v2.y); w1.y = pk16(v2.z, v2.w);
    w1.z = pk16(v3.x, v3.y); w1.w = pk16(v3.z, v3.w);
    *(uint4*)&As[m_st * 40 + part * 16 + 0] = w0;
    *(uint4*)&As[m_st * 40 + part * 16 + 8] = w1;
    __syncthreads();

    h8 af[4], bf[4];
#pragma unroll
    for (int mf = 0; mf < 4; ++mf)
      af[mf] = *(const h8*)&As[(wm * 64 + mf * 16 + fr) * 40 + fq * 8];
#pragma unroll
    for (int nf = 0; nf < 4; ++nf)
      bf[nf] = *(const h8*)&wt_g[z][(size_t)(by * 128 + wn * 64 + nf * 16 + fr) * DD +
                                    kt * 32 + fq * 8];
#pragma unroll
    for (int mf = 0; mf < 4; ++mf)
#pragma unroll
      for (int nf = 0; nf < 4; ++nf)
        acc[mf][nf] = __builtin_amdgcn_mfma_f32_16x16x32_f16(
            af[mf], bf[nf], acc[mf][nf], 0, 0, 0);
    __syncthreads();
  }

  // epilogue: z=0 -> xp (low half), z=1 -> sigmoid(acc+bg) (high half)
#pragma unroll
  for (int nf = 0; nf < 4; ++nf) {
    const int col = by * 128 + wn * 64 + nf * 16 + fr;
    const float bias = z ? bgv[col] : 0.0f;
#pragma unroll
    for (int mf = 0; mf < 4; ++mf) {
#pragma unroll
      for (int r = 0; r < 4; ++r) {
        const int row = bx * 128 + wm * 64 + mf * 16 + fq * 4 + r;
        float v = acc[mf][nf][r];
        if (z) v = sigmoid_fast(v + bias);
        out[((size_t)row * HH + col) * 2 + z] = (_Float16)v;
      }
    }
  }
}

// ---------- kernel 3: sequential gated recurrence + LayerNorm ----------
// One block per batch row. Thread h owns output feature h.
// W' = diag(gamma) applied to Wh rows, kept as 128 f16x2 pairs in VGPRs.
// hn_{t-1} @ Wh = s*dot(hr_{t-1}, W'col) - s*mu*cg + cb  (LN absorbed).
__global__ __launch_bounds__(256, 1) void rnn_kernel(
    const float* __restrict__ Wh, const float* __restrict__ gamma,
    const float* __restrict__ beta, u32* __restrict__ io) {
  const int b = blockIdx.x;
  const int h = threadIdx.x;
  const int wv = h >> 6;

  __shared__ __align__(16) u32 hbuf[2][128];   // packed f16x2 raw-h double buffer
  __shared__ __align__(16) float4 pbuf[2][2];  // 4 waves x (sum,sumsq), double buffered

  // ---- init: load Wh column h, absorb gamma, colsums ----
  const float gm = gamma[h], bt = beta[h];
  float cg = 0.0f, cb = 0.0f;
  u32 wp[128];
#pragma unroll
  for (int j = 0; j < 128; ++j) {
    const float r0 = Wh[(2 * j) * HH + h];
    const float r1 = Wh[(2 * j + 1) * HH + h];
    const float w0 = r0 * gamma[2 * j];
    const float w1 = r1 * gamma[2 * j + 1];
    cg += w0 + w1;
    cb = fmaf(beta[2 * j], r0, cb);
    cb = fmaf(beta[2 * j + 1], r1, cb);
    wp[j] = pk16(w0, w1);
  }

  u32* __restrict__ xin = io + (size_t)b * TT * HH + h;
  float* __restrict__ outp = (float*)io + (size_t)b * TT * HH + h;

  // ---- prologue (t = 0, prev_h = 0) ----
  u32 xg0 = xin[0];
  u32 xgn1 = xin[HH];
  u32 xgn2 = xin[2 * HH];
  float xp = lo16f(xg0), gt = hi16f(xg0);
  float hr = gt * tanh_fast(xp);  // hr_0
  float oth = __shfl_xor(hr, 1);
  float s1 = hr + oth;
  float q1 = fmaf(hr, hr, oth * oth);
  {
    const float lo = (h & 1) ? oth : hr;
    const float hi = (h & 1) ? hr : oth;
    if (!(h & 1)) hbuf[0][h >> 1] = pk16(lo, hi);
  }
  xp = lo16f(xgn1); gt = hi16f(xgn1);
  xgn1 = xgn2;
  xgn2 = xin[(size_t)3 * HH];
  int p = 0;

  for (int t = 1; t < TT; ++t) {
    // finish wave butterfly of (sum, sumsq) of hr_{t-1}
    float s = s1, q = q1;
#pragma unroll
    for (int d = 2; d < 64; d <<= 1) {
      s += __shfl_xor(s, d);
      q += __shfl_xor(q, d);
    }
    if ((h & 63) == 0) ((float2*)&pbuf[p][0])[wv] = make_float2(s, q);
    const int tf = (t + 3 < TT) ? (t + 3) : (TT - 1);
    const u32 xg_ld = xin[(size_t)tf * HH];  // prefetch distance 3
    __syncthreads();

    // matmul on raw h (gamma-absorbed), broadcast LDS reads
    float a0 = 0.f, a1 = 0.f, a2 = 0.f, a3 = 0.f;
    const uint4* __restrict__ hb = (const uint4*)&hbuf[p][0];
#pragma unroll
    for (int j = 0; j < 32; ++j) {
      const uint4 v = hb[j];
      a0 = dot2_(wp[4 * j + 0], v.x, a0);
      a1 = dot2_(wp[4 * j + 1], v.y, a1);
      a2 = dot2_(wp[4 * j + 2], v.z, a2);
      a3 = dot2_(wp[4 * j + 3], v.w, a3);
    }

    const float4 P0 = pbuf[p][0], P1 = pbuf[p][1];
    const float S = (P0.x + P0.z) + (P1.x + P1.z);
    const float Q = (P0.y + P0.w) + (P1.y + P1.w);
    const float mu = S * (1.0f / 256.0f);
    const float var = Q * (1.0f / 256.0f) - mu * mu;
    const float sinv = rsq_(var + 1e-3f);

    const float acc = (a0 + a1) + (a2 + a3);
    const float zz = fmaf(sinv, acc, fmaf(-(sinv * mu), cg, cb)) + xp;
    const float cand = tanh_fast(zz);
    const float hn = fmaf((hr - mu) * sinv, gm, bt);  // hn_{t-1}[h]
    outp[(size_t)(t - 1) * HH] = hn;
    const float hrn = fmaf(gt, cand - hn, hn);  // hr_t

    const u32 xgc = xgn1;
    xgn1 = xgn2; xgn2 = xg_ld;
    xp = lo16f(xgc); gt = hi16f(xgc);

    const float o2 = __shfl_xor(hrn, 1);
    s1 = hrn + o2;
    q1 = fmaf(hrn, hrn, o2 * o2);
    const float lo = (h & 1) ? o2 : hrn;
    const float hi = (h & 1) ? hrn : o2;
    if (!(h & 1)) hbuf[p ^ 1][h >> 1] = pk16(lo, hi);
    hr = hrn;
    p ^= 1;
  }

  // ---- epilogue: LN for hr_{T-1} ----
  {
    float s = s1, q = q1;
#pragma unroll
    for (int d = 2; d < 64; d <<= 1) {
      s += __shfl_xor(s, d);
      q += __shfl_xor(q, d);
    }
    if ((h & 63) == 0) ((float2*)&pbuf[p][0])[wv] = make_float2(s, q);
    __syncthreads();
    const float4 P0 = pbuf[p][0], P1 = pbuf[p][1];
    const float S = (P0.x + P0.z) + (P1.x + P1.z);
    const float Q = (P0.y + P0.w) + (P1.y + P1.w);
    const float mu = S * (1.0f / 256.0f);
    const float var = Q * (1.0f / 256.0f) - mu * mu;
    const float sinv = rsq_(var + 1e-3f);
    outp[(size_t)(TT - 1) * HH] = fmaf((hr - mu) * sinv, gm, bt);
  }
}

extern "C" void kernel_launch(void* const* d_in, const int* in_sizes, int n_in,
                              void* d_out, int out_size, void* d_ws,
                              size_t ws_size, hipStream_t stream) {
  const float* x = (const float*)d_in[0];
  const float* g = (const float*)d_in[1];
  const float* Wg = (const float*)d_in[2];
  const float* bg = (const float*)d_in[3];
  const float* Wx = (const float*)d_in[4];
  const float* Wh = (const float*)d_in[5];
  const float* gamma = (const float*)d_in[6];
  const float* beta = (const float*)d_in[7];

  prep_wt_kernel<<<dim3(256, 2), 256, 0, stream>>>(Wx, Wg);
  gemm_kernel<<<dim3(4, 1024), 256, 0, stream>>>(x, g, bg, (_Float16*)d_out);
  rnn_kernel<<<dim3(BB), 256, 0, stream>>>(Wh, gamma, beta, (u32*)d_out);
}